// Round 18
// baseline (168.635 us; speedup 1.0000x reference)
//
#include <hip/hip_runtime.h>
#include <math.h>

typedef unsigned short u16;
typedef __bf16 bf16x8 __attribute__((ext_vector_type(8)));
typedef float f32x4 __attribute__((ext_vector_type(4)));
typedef u16 u16x4 __attribute__((ext_vector_type(4)));
typedef u16 u16x8 __attribute__((ext_vector_type(8)));

#define DEV __device__ __forceinline__

DEV u16 f2bf(float f) {
  unsigned u = __builtin_bit_cast(unsigned, f);
  u += 0x7FFFu + ((u >> 16) & 1u);
  return (u16)(u >> 16);
}
DEV float bf2f(u16 b) {
  unsigned u = ((unsigned)b) << 16;
  return __builtin_bit_cast(float, u);
}

DEV void gload16(const void* g, void* l) {
  __builtin_amdgcn_global_load_lds((__attribute__((address_space(1))) void*)g,
                                   (__attribute__((address_space(3))) void*)l, 16, 0, 0);
}

// ---------------- fused prep: LN1 (blocks 0..2047) + weight cvt (blocks 2048+) --------
__launch_bounds__(256)
__global__ void prep(const float* __restrict__ x, const float* __restrict__ gam,
                     const float* __restrict__ bet, u16* __restrict__ hout,
                     const float* __restrict__ wq, const float* __restrict__ wk,
                     const float* __restrict__ wv, const float* __restrict__ wo,
                     const float* __restrict__ f1, const float* __restrict__ f2,
                     u16* __restrict__ dq, u16* __restrict__ dk, u16* __restrict__ dv,
                     u16* __restrict__ dwo, u16* __restrict__ df1, u16* __restrict__ df2) {
  int t = threadIdx.x;
  if (blockIdx.x < 2048) {
    int row = blockIdx.x;
    float4 v = ((const float4*)(x + (size_t)row * 1024))[t];
    float s = v.x + v.y + v.z + v.w;
    float s2 = v.x * v.x + v.y * v.y + v.z * v.z + v.w * v.w;
    for (int off = 1; off < 64; off <<= 1) {
      s += __shfl_xor(s, off);
      s2 += __shfl_xor(s2, off);
    }
    __shared__ float red[8];
    int wv0 = t >> 6, ln = t & 63;
    if (ln == 0) { red[wv0] = s; red[wv0 + 4] = s2; }
    __syncthreads();
    s = red[0] + red[1] + red[2] + red[3];
    s2 = red[4] + red[5] + red[6] + red[7];
    float mu = s * (1.f / 1024.f);
    float var = s2 * (1.f / 1024.f) - mu * mu;
    float rs = rsqrtf(var + 1e-5f);
    float4 gv = ((const float4*)gam)[t];
    float4 bv = ((const float4*)bet)[t];
    u16x4 o = { f2bf((v.x - mu) * rs * gv.x + bv.x), f2bf((v.y - mu) * rs * gv.y + bv.y),
                f2bf((v.z - mu) * rs * gv.z + bv.z), f2bf((v.w - mu) * rs * gv.w + bv.w) };
    ((u16x4*)(hout + (size_t)row * 1024))[t] = o;
  } else {
    int i = (blockIdx.x - 2048) * 256 + t;
    const float* src;
    u16* dst;
    int local;
    if (i < (1 << 18)) { src = wq; dst = dq; local = i; }
    else if (i < (2 << 18)) { src = wk; dst = dk; local = i - (1 << 18); }
    else if (i < (3 << 18)) { src = wv; dst = dv; local = i - (2 << 18); }
    else if (i < (4 << 18)) { src = wo; dst = dwo; local = i - (3 << 18); }
    else if (i < (4 << 18) + (1 << 20)) { src = f1; dst = df1; local = i - (4 << 18); }
    else { src = f2; dst = df2; local = i - ((4 << 18) + (1 << 20)); }
    float4 v = ((const float4*)src)[local];
    u16x4 o = { f2bf(v.x), f2bf(v.y), f2bf(v.z), f2bf(v.w) };
    ((u16x4*)dst)[local] = o;
  }
}

// ---------------- fused: x2 = x + sum of 4 bf16 wo-partials; h2 = LN(x2) ----------
__launch_bounds__(256)
__global__ void ln2_add(const float* __restrict__ x, const u16* __restrict__ Pw,
                        size_t poff, const float* __restrict__ gam,
                        const float* __restrict__ bet, float* __restrict__ x2,
                        u16* __restrict__ out) {
  int row = blockIdx.x;
  int t = threadIdx.x;
  size_t base = (size_t)row * 256 + t;
  float4 v = ((const float4*)x)[base];
#pragma unroll
  for (int i = 0; i < 4; ++i) {
    u16x4 q = ((const u16x4*)(Pw + i * poff))[base];
    v.x += bf2f(q[0]);
    v.y += bf2f(q[1]);
    v.z += bf2f(q[2]);
    v.w += bf2f(q[3]);
  }
  ((float4*)x2)[base] = v;
  float s = v.x + v.y + v.z + v.w;
  float s2 = v.x * v.x + v.y * v.y + v.z * v.z + v.w * v.w;
  for (int off = 1; off < 64; off <<= 1) {
    s += __shfl_xor(s, off);
    s2 += __shfl_xor(s2, off);
  }
  __shared__ float red[8];
  int wv = t >> 6, ln = t & 63;
  if (ln == 0) { red[wv] = s; red[wv + 4] = s2; }
  __syncthreads();
  s = red[0] + red[1] + red[2] + red[3];
  s2 = red[4] + red[5] + red[6] + red[7];
  float mu = s * (1.f / 1024.f);
  float var = s2 * (1.f / 1024.f) - mu * mu;
  float rs = rsqrtf(var + 1e-5f);
  float4 gv = ((const float4*)gam)[t];
  float4 bv = ((const float4*)bet)[t];
  u16x4 o = { f2bf((v.x - mu) * rs * gv.x + bv.x), f2bf((v.y - mu) * rs * gv.y + bv.y),
              f2bf((v.z - mu) * rs * gv.z + bv.z), f2bf((v.w - mu) * rs * gv.w + bv.w) };
  ((u16x4*)(out + (size_t)row * 1024))[t] = o;
}

// ---------------- final: out = x2 + b2 + sum of 4 ff2 partials ----------------
__launch_bounds__(256)
__global__ void final_add(const float* __restrict__ x2, const float* __restrict__ b2,
                          const u16* __restrict__ Qp, size_t qoff,
                          float* __restrict__ out) {
  int row = blockIdx.x;
  int t = threadIdx.x;
  size_t base = (size_t)row * 256 + t;
  float4 xv = ((const float4*)x2)[base];
  float4 bv = ((const float4*)b2)[t];
  float4 o = { xv.x + bv.x, xv.y + bv.y, xv.z + bv.z, xv.w + bv.w };
#pragma unroll
  for (int i = 0; i < 4; ++i) {
    u16x4 q = ((const u16x4*)(Qp + i * qoff))[base];
    o.x += bf2f(q[0]);
    o.y += bf2f(q[1]);
    o.z += bf2f(q[2]);
    o.w += bf2f(q[3]);
  }
  ((float4*)out)[base] = o;
}

// ---------------- V transpose ----------------
__launch_bounds__(256)
__global__ void transpose_v(const u16* __restrict__ V, u16* __restrict__ Vt) {
  const int st = blockIdx.x, h = blockIdx.y;
  __shared__ u16 tile[64][72];
  const int t = threadIdx.x;
  const int r = t >> 3, c8 = t & 7;
#pragma unroll
  for (int i = 0; i < 2; ++i) {
    int row = i * 32 + r;
    *(u16x8*)&tile[row][c8 * 8] =
        *(const u16x8*)&V[(size_t)(st * 64 + row) * 1024 + h * 64 + c8 * 8];
  }
  __syncthreads();
#pragma unroll
  for (int i = 0; i < 2; ++i) {
    int d = i * 32 + r;
    u16x8 o;
#pragma unroll
    for (int jj = 0; jj < 8; ++jj) o[jj] = tile[c8 * 8 + jj][d];
    *(u16x8*)&Vt[(size_t)(h * 64 + d) * 2048 + st * 64 + c8 * 8] = o;
  }
}

// ---------------- generic bf16 GEMM: double-buffered prefetch staging ----------------
// Staging discipline copied from attn_fwd (R9-proven): issue tile kt+1's
// global_load_lds into buf^1 BEFORE computing tile kt; single barrier per
// iteration (its vmcnt(0) drain covers the prefetch; buffer reuse is 2
// barriers away). Was: stage->sync->compute->sync with latency fully exposed.
template <int BM, int BN, int WR, int WC, int EPI, int SPLITK, int SWZ>
__launch_bounds__(256, 2)
__global__ void gemm_bt(const u16* __restrict__ A, const u16* __restrict__ B,
                        void* __restrict__ C, const float* __restrict__ bias,
                        const float* __restrict__ resid, int M, int N, int K,
                        size_t zoff) {
  constexpr int FM = BM / WR / 16;
  constexpr int FN = BN / WC / 16;
  __shared__ u16 As[2][BM * 32];
  __shared__ u16 Bs[2][BN * 32];
  int bxi = blockIdx.x, byi = blockIdx.y, bzi = blockIdx.z;
  if constexpr (SWZ == 1) {
    int bid = bxi + 8 * (byi + (int)gridDim.y * bzi);
    int xcd = bid & 7, k = bid >> 3;
    bxi = xcd;
    byi = k % (int)gridDim.y;
    bzi = k / (int)gridDim.y;
  } else if constexpr (SWZ == 2) {
    int bid = bxi + 32 * blockIdx.y;
    int xcd = bid & 7, k = bid >> 3;
    bxi = xcd * 4 + (k & 3);
    byi = k >> 2;
    bzi = 0;
  }
  const int t = threadIdx.x, lane = t & 63, w = t >> 6;
  const int wr = w / WC, wc = w % WC;
  const int g = lane >> 4, l16 = lane & 15;
  const int m0 = byi * BM, n0 = bxi * BN;
  const int ks = K / SPLITK;
  const int k0 = (SPLITK > 1) ? bzi * ks : 0;
  const size_t cbase = (SPLITK > 1) ? (size_t)bzi * zoff : 0;
  f32x4 acc[FM][FN] = {};
  const int nkt = ks >> 5;

  auto stage = [&](int buf, int kt) {
    const u16* Ag = A + (size_t)m0 * K + k0 + kt * 32;
    const u16* Bg = B + (size_t)n0 * K + k0 + kt * 32;
#pragma unroll
    for (int i = 0; i < BM / 64; ++i) {
      int c = i * 256 + t;
      gload16(Ag + (size_t)(c >> 2) * K + (c & 3) * 8, &As[buf][(i * 256 + w * 64) * 8]);
    }
#pragma unroll
    for (int i = 0; i < BN / 64; ++i) {
      int c = i * 256 + t;
      gload16(Bg + (size_t)(c >> 2) * K + (c & 3) * 8, &Bs[buf][(i * 256 + w * 64) * 8]);
    }
  };

  stage(0, 0);
  __syncthreads();
  int cur = 0;
  for (int kt = 0; kt < nkt; ++kt) {
    if (kt + 1 < nkt) stage(cur ^ 1, kt + 1);
    bf16x8 af[FM], bfr[FN];
#pragma unroll
    for (int m = 0; m < FM; ++m)
      af[m] = *(const bf16x8*)&As[cur][(wr * FM * 16 + m * 16 + l16) * 32 + g * 8];
#pragma unroll
    for (int n = 0; n < FN; ++n)
      bfr[n] = *(const bf16x8*)&Bs[cur][(wc * FN * 16 + n * 16 + l16) * 32 + g * 8];
#pragma unroll
    for (int m = 0; m < FM; ++m)
#pragma unroll
      for (int n = 0; n < FN; ++n)
        acc[m][n] = __builtin_amdgcn_mfma_f32_16x16x32_bf16(af[m], bfr[n], acc[m][n], 0, 0, 0);
    __syncthreads();
    cur ^= 1;
  }
#pragma unroll
  for (int m = 0; m < FM; ++m)
#pragma unroll
    for (int n = 0; n < FN; ++n)
#pragma unroll
      for (int r = 0; r < 4; ++r) {
        int row = m0 + wr * FM * 16 + m * 16 + g * 4 + r;
        int col = n0 + wc * FN * 16 + n * 16 + l16;
        size_t idx = (size_t)row * N + col;
        float v = acc[m][n][r];
        if constexpr (EPI == 0) {
          ((u16*)C)[cbase + idx] = f2bf(v);
        } else if constexpr (EPI == 1) {
          v += bias[col];
          v = 0.5f * v * (1.f + erff(v * 0.70710678118f));
          ((u16*)C)[idx] = f2bf(v);
        } else if constexpr (EPI == 2) {
          ((float*)C)[idx] = v + bias[col] + resid[idx];
        } else if constexpr (EPI == 3) {
          ((float*)C)[idx] = v + resid[idx];
        } else {
          ((float*)C)[cbase + idx] = v;
        }
      }
}

// ---------------- fused QKV projection, 64x128 tiles, dbuf prefetch ----------------
__launch_bounds__(256, 2)
__global__ void gemm_qkv64(const u16* __restrict__ A, const u16* __restrict__ B0,
                           const u16* __restrict__ B1, const u16* __restrict__ B2,
                           u16* __restrict__ C0, u16* __restrict__ C1, u16* __restrict__ C2) {
  constexpr int FM = 4, FN = 2;
  const int K = 1024, N = 1024;
  int bid = blockIdx.x + 24 * blockIdx.y;
  int xcd = bid & 7, kk0 = bid >> 3;
  const int bxs = xcd * 3 + kk0 % 3;
  const int bys = kk0 / 3;
  const int which = bxs >> 3;
  const u16* B = which == 0 ? B0 : which == 1 ? B1 : B2;
  u16* C = which == 0 ? C0 : which == 1 ? C1 : C2;
  __shared__ u16 As[2][64 * 32];
  __shared__ u16 Bs[2][128 * 32];
  const int t = threadIdx.x, lane = t & 63, w = t >> 6;
  const int wc = w;
  const int g = lane >> 4, l16 = lane & 15;
  const int m0 = bys * 64, n0 = (bxs & 7) * 128;
  f32x4 acc[FM][FN] = {};

  auto stage = [&](int buf, int kt) {
    const u16* Ag = A + (size_t)m0 * K + kt * 32;
    const u16* Bg = B + (size_t)n0 * K + kt * 32;
    {
      int c = t;
      gload16(Ag + (size_t)(c >> 2) * K + (c & 3) * 8, &As[buf][(w * 64) * 8]);
    }
#pragma unroll
    for (int i = 0; i < 2; ++i) {
      int c = i * 256 + t;
      gload16(Bg + (size_t)(c >> 2) * K + (c & 3) * 8, &Bs[buf][(i * 256 + w * 64) * 8]);
    }
  };

  stage(0, 0);
  __syncthreads();
  int cur = 0;
  for (int kt = 0; kt < 32; ++kt) {
    if (kt + 1 < 32) stage(cur ^ 1, kt + 1);
    bf16x8 af[FM], bfr[FN];
#pragma unroll
    for (int m = 0; m < FM; ++m)
      af[m] = *(const bf16x8*)&As[cur][(m * 16 + l16) * 32 + g * 8];
#pragma unroll
    for (int n = 0; n < FN; ++n)
      bfr[n] = *(const bf16x8*)&Bs[cur][(wc * FN * 16 + n * 16 + l16) * 32 + g * 8];
#pragma unroll
    for (int m = 0; m < FM; ++m)
#pragma unroll
      for (int n = 0; n < FN; ++n)
        acc[m][n] = __builtin_amdgcn_mfma_f32_16x16x32_bf16(af[m], bfr[n], acc[m][n], 0, 0, 0);
    __syncthreads();
    cur ^= 1;
  }
#pragma unroll
  for (int m = 0; m < FM; ++m)
#pragma unroll
    for (int n = 0; n < FN; ++n)
#pragma unroll
      for (int r = 0; r < 4; ++r) {
        int row = m0 + m * 16 + g * 4 + r;
        int col = n0 + wc * FN * 16 + n * 16 + l16;
        C[(size_t)row * N + col] = f2bf(acc[m][n][r]);
      }
}

// ---------------- flash attention: 768 blocks (3/CU), 11 tiles each (R16) -------------
__launch_bounds__(256, 4)
__global__ void attn_fwd(const u16* __restrict__ Q, const u16* __restrict__ Kb,
                         const u16* __restrict__ Vt, const float* __restrict__ slopes,
                         u16* __restrict__ BoLo, u16* __restrict__ BoHi,
                         float* __restrict__ BlG) {
  const int p = blockIdx.x;
  const int h = blockIdx.y;
  const int z = blockIdx.z;
  const int t = threadIdx.x, lane = t & 63, w = t >> 6;
  const int g = lane >> 4, l16 = lane & 15;
  const float slope = slopes[h];
  const int TA = p + 1;
  const int qbB = 31 - p;

  __shared__ u16 Ks[2][4096];
  __shared__ u16 Vs[2][4096];
  __shared__ u16 Ps[4][16][72];

  const int r0 = w * 8 + (lane >> 3), r1 = 32 + r0;
  const int c8 = lane & 7;
  const int c0s = c8 ^ (r0 & 7), c1s = c8 ^ (r1 & 7);
  const int sw = l16 & 7;
  const u16x8 ones_u = { 0x3F80, 0x3F80, 0x3F80, 0x3F80, 0x3F80, 0x3F80, 0x3F80, 0x3F80 };
  const bf16x8 ones = __builtin_bit_cast(bf16x8, ones_u);

  auto stage = [&](int buf, int kv0) {
    gload16(Kb + (size_t)(kv0 + r0) * 1024 + h * 64 + c0s * 8, &Ks[buf][(w * 64) * 8]);
    gload16(Kb + (size_t)(kv0 + r1) * 1024 + h * 64 + c1s * 8, &Ks[buf][(256 + w * 64) * 8]);
    gload16(Vt + (size_t)(h * 64 + r0) * 2048 + kv0 + c0s * 8, &Vs[buf][(w * 64) * 8]);
    gload16(Vt + (size_t)(h * 64 + r1) * 2048 + kv0 + c1s * 8, &Vs[buf][(256 + w * 64) * 8]);
  };
  auto kvOf = [&](int idx) { return idx < TA ? idx * 64 : (idx - TA) * 64; };
  auto boPtr = [&](size_t slot) {
    return slot < 1024 ? BoLo + slot * 4096 : BoHi + (slot - 1024) * 4096;
  };

  const int myStart = z * 11;
  const int myEnd = myStart + 11;
  const size_t slotBase = (((size_t)p * 16 + h) * 3 + z) * 2;

  bool flushed[2] = { false, false };
  f32x4 o_acc[4] = {};
  f32x4 lsum = {};

  auto flush = [&](int c) {
    u16* Bo = boPtr(slotBase + c);
    float* Bl = BlG + (slotBase + c) * 64;
#pragma unroll
    for (int d = 0; d < 4; ++d)
#pragma unroll
      for (int r = 0; r < 4; ++r)
        Bo[(w * 16 + g * 4 + r) * 64 + d * 16 + l16] = f2bf(o_acc[d][r]);
    if (l16 == 0) {
#pragma unroll
      for (int r = 0; r < 4; ++r) Bl[w * 16 + g * 4 + r] = lsum[r];
    }
    flushed[c] = true;
  };

  int qb = (myStart < TA) ? p : qbB;
  int q0 = qb * 64 + w * 16;
  bf16x8 qf[2];
#pragma unroll
  for (int kk = 0; kk < 2; ++kk)
    qf[kk] = *(const bf16x8*)&Q[(size_t)(q0 + l16) * 1024 + h * 64 + kk * 32 + g * 8];

  stage(0, kvOf(myStart));
  __syncthreads();

  int cur = 0;
  for (int it = 0; it < 11; ++it) {
    const int idx = myStart + it;
    if (idx == TA && myStart < TA) {
      flush(0);
      qb = qbB;
      q0 = qb * 64 + w * 16;
#pragma unroll
      for (int kk = 0; kk < 2; ++kk)
        qf[kk] = *(const bf16x8*)&Q[(size_t)(q0 + l16) * 1024 + h * 64 + kk * 32 + g * 8];
#pragma unroll
      for (int d = 0; d < 4; ++d) o_acc[d] = f32x4{};
      lsum = f32x4{};
    }
    if (it + 1 < 11) stage(cur ^ 1, kvOf(idx + 1));
    {
      const int kv0 = kvOf(idx);
      const bool lastT = (idx == TA - 1) || (idx == 32);
      f32x4 s[4];
      __builtin_amdgcn_s_setprio(1);
#pragma unroll
      for (int n = 0; n < 4; ++n) {
        bf16x8 kf0 = *(const bf16x8*)&Ks[cur][(n * 16 + l16) * 64 + ((g ^ sw) * 8)];
        bf16x8 kf1 = *(const bf16x8*)&Ks[cur][(n * 16 + l16) * 64 + (((4 + g) ^ sw) * 8)];
        f32x4 z4 = {};
        s[n] = __builtin_amdgcn_mfma_f32_16x16x32_bf16(qf[0], kf0, z4, 0, 0, 0);
        s[n] = __builtin_amdgcn_mfma_f32_16x16x32_bf16(qf[1], kf1, s[n], 0, 0, 0);
      }
      __builtin_amdgcn_s_setprio(0);
      const float aB = -slope * (float)(kv0 + l16);
#pragma unroll
      for (int n = 0; n < 4; ++n) {
        const float aN = aB - slope * (float)(n * 16);
        const int kj = kv0 + n * 16 + l16;
        u16x4 pr;
#pragma unroll
        for (int r = 0; r < 4; ++r) {
          float val = fmaf(s[n][r], 0.125f, aN);
          if (lastT) {
            int qi = q0 + g * 4 + r;
            val = (kj <= qi) ? val : -1e30f;
          }
          pr[r] = f2bf(__expf(val));
        }
#pragma unroll
        for (int r = 0; r < 4; ++r) Ps[w][g * 4 + r][n * 16 + l16] = pr[r];
      }
      bf16x8 pf[2];
#pragma unroll
      for (int kk = 0; kk < 2; ++kk)
        pf[kk] = *(const bf16x8*)&Ps[w][l16][kk * 32 + g * 8];
      __builtin_amdgcn_s_setprio(1);
#pragma unroll
      for (int kk = 0; kk < 2; ++kk)
        lsum = __builtin_amdgcn_mfma_f32_16x16x32_bf16(pf[kk], ones, lsum, 0, 0, 0);
#pragma unroll
      for (int d = 0; d < 4; ++d) {
#pragma unroll
        for (int kk = 0; kk < 2; ++kk) {
          bf16x8 vv = *(const bf16x8*)&Vs[cur][(d * 16 + l16) * 64 + (((kk * 4 + g) ^ sw) * 8)];
          o_acc[d] = __builtin_amdgcn_mfma_f32_16x16x32_bf16(pf[kk], vv, o_acc[d], 0, 0, 0);
        }
      }
      __builtin_amdgcn_s_setprio(0);
    }
    __syncthreads();
    cur ^= 1;
  }
  flush((myEnd - 1) < TA ? 0 : 1);
#pragma unroll
  for (int c = 0; c < 2; ++c)
    if (!flushed[c]) {
      u16* Bo = boPtr(slotBase + c);
      float* Bl = BlG + (slotBase + c) * 64;
#pragma unroll
      for (int i = 0; i < 16; ++i) Bo[i * 256 + t] = 0;
      if (t < 64) Bl[t] = 0.f;
    }
}

// ---------------- merge 3 z-partials per chunk -> attnO ----------------
__launch_bounds__(256)
__global__ void merge_b(const u16* __restrict__ BoLo, const u16* __restrict__ BoHi,
                        const float* __restrict__ BlG, u16* __restrict__ O) {
  const int p = blockIdx.x, h = blockIdx.y;
  const int t = threadIdx.x;
  const int row = t >> 2, c0 = (t & 3) * 16;
  const size_t base = ((size_t)p * 16 + h) * 6;
#pragma unroll
  for (int c = 0; c < 2; ++c) {
    const int qb = c == 0 ? p : 31 - p;
    float l = 0.f;
    float acc[16];
#pragma unroll
    for (int i = 0; i < 16; ++i) acc[i] = 0.f;
#pragma unroll
    for (int z = 0; z < 3; ++z) {
      const size_t slot = base + (size_t)z * 2 + c;
      l += BlG[slot * 64 + row];
      const u16* Bo = (slot < 1024 ? BoLo + slot * 4096 : BoHi + (slot - 1024) * 4096) +
                      row * 64 + c0;
#pragma unroll
      for (int i = 0; i < 16; ++i) acc[i] += bf2f(Bo[i]);
    }
    float inv = 1.f / l;
    u16x8 o0, o1;
#pragma unroll
    for (int i = 0; i < 8; ++i) {
      o0[i] = f2bf(acc[i] * inv);
      o1[i] = f2bf(acc[8 + i] * inv);
    }
    u16* dst = O + (size_t)(qb * 64 + row) * 1024 + h * 64 + c0;
    *(u16x8*)dst = o0;
    *(u16x8*)(dst + 8) = o1;
  }
}

// ---------------- launcher ----------------
extern "C" void kernel_launch(void* const* d_in, const int* in_sizes, int n_in,
                              void* d_out, int out_size, void* d_ws, size_t ws_size,
                              hipStream_t stream) {
  const float* x = (const float*)d_in[0];
  const float* slopes = (const float*)d_in[1];
  const float* wq = (const float*)d_in[2];
  const float* wk = (const float*)d_in[3];
  const float* wv = (const float*)d_in[4];
  const float* wo = (const float*)d_in[5];
  const float* ff1w = (const float*)d_in[6];
  const float* ff1b = (const float*)d_in[7];
  const float* ff2w = (const float*)d_in[8];
  const float* ff2b = (const float*)d_in[9];
  const float* ln1g = (const float*)d_in[10];
  const float* ln1b = (const float*)d_in[11];
  const float* ln2g = (const float*)d_in[12];
  const float* ln2b = (const float*)d_in[13];
  float* out = (float*)d_out;

  if (ws_size < (size_t)(56u << 20)) return;  // need 56MB scratch

  char* ws = (char*)d_ws;
  // Region plan (time-ordered): identical to R16.
  u16* hbuf = (u16*)(ws + 0);
  u16* Qb = (u16*)(ws + (4u << 20));
  u16* Kbf = (u16*)(ws + (8u << 20));
  u16* Vbf = (u16*)(ws + (12u << 20));
  u16* Vtb = (u16*)(ws + (16u << 20));
  u16* Pw = (u16*)(ws + (4u << 20));
  u16* ffact = Qb;
  u16* BoLo = (u16*)(ws + (20u << 20));
  u16* BoHi = (u16*)(ws + (12u << 20));
  float* x2 = (float*)(ws + (20u << 20));
  float* BlG = (float*)(ws + (28u << 20));
  u16* h2 = (u16*)(ws + (28u << 20));
  u16* wqb = (u16*)(ws + (32u << 20));
  u16* wkb = (u16*)(ws + (34u << 20));
  u16* wvb = (u16*)(ws + (36u << 20));
  u16* wob = (u16*)(ws + (38u << 20));
  u16* ff1wb = (u16*)(ws + (40u << 20));
  u16* ff2wb = (u16*)(ws + (48u << 20));
  u16* attnO = hbuf;
  u16* Qp = (u16*)(ws + (32u << 20));
  const size_t q4off = (size_t)(4u << 20) / 2;
  const size_t woff = (size_t)2048 * 1024;

  prep<<<2048 + 12288, 256, 0, stream>>>(x, ln1g, ln1b, hbuf, wq, wk, wv, wo, ff1w, ff2w,
                                         wqb, wkb, wvb, wob, ff1wb, ff2wb);
  gemm_qkv64<<<dim3(24, 32), 256, 0, stream>>>(hbuf, wqb, wkb, wvb, Qb, Kbf, Vbf);
  transpose_v<<<dim3(32, 16), 256, 0, stream>>>(Vbf, Vtb);
  attn_fwd<<<dim3(16, 16, 3), 256, 0, stream>>>(Qb, Kbf, Vtb, slopes, BoLo, BoHi, BlG);
  merge_b<<<dim3(16, 16), 256, 0, stream>>>(BoLo, BoHi, BlG, attnO);
  gemm_bt<64, 128, 1, 4, 0, 4, 1><<<dim3(8, 32, 4), 256, 0, stream>>>(
      attnO, wob, Pw, nullptr, nullptr, 2048, 1024, 1024, woff);
  ln2_add<<<2048, 256, 0, stream>>>(x, Pw, woff, ln2g, ln2b, x2, h2);
  gemm_bt<64, 128, 1, 4, 1, 1, 0><<<dim3(32, 32), 256, 0, stream>>>(
      h2, ff1wb, ffact, ff1b, nullptr, 2048, 4096, 1024, 0);
  gemm_bt<64, 128, 1, 4, 0, 4, 1><<<dim3(8, 32, 4), 256, 0, stream>>>(
      ffact, ff2wb, Qp, nullptr, nullptr, 2048, 1024, 4096, q4off);
  final_add<<<2048, 256, 0, stream>>>(x2, ff2b, Qp, q4off, out);
}